// Round 6
// baseline (110.795 us; speedup 1.0000x reference)
//
#include <hip/hip_runtime.h>

typedef __attribute__((ext_vector_type(8))) short bf16x8;
typedef __attribute__((ext_vector_type(4))) float f32x4;

__device__ __forceinline__ unsigned int f2bf(float f) {
    union { float f; unsigned int u; } v; v.f = f;
    unsigned int u = v.u;
    u += 0x7FFFu + ((u >> 16) & 1u);   // round-to-nearest-even
    return u >> 16;
}

// Pack lin1_W [256][256] f32 (row-major, W[k][n]) into bf16 MFMA-B-fragment order,
// F-MAJOR: 16B unit index tid = (f*8 + kt)*64 + lane holds
//   { W[kt*32 + (lane>>4)*8 + j][f*16 + (lane&15)] : j = 0..7 }
__global__ void pack_w_kernel(const float* __restrict__ W, unsigned short* __restrict__ P) {
    int tid = blockIdx.x * blockDim.x + threadIdx.x;
    if (tid >= 8192) return;
    int f    = tid >> 9;
    int kt   = (tid >> 6) & 7;
    int lane = tid & 63;
    int k0  = kt * 32 + (lane >> 4) * 8;
    int col = f * 16 + (lane & 15);
    bf16x8 v;
    #pragma unroll
    for (int j = 0; j < 8; ++j)
        v[j] = (short)f2bf(W[(k0 + j) * 256 + col]);
    ((bf16x8*)P)[tid] = v;
}

// Barrier-free, LDS-free. Each wave owns 32 rows (two 16-row MFMA tiles) and
// streams W once per 32 rows: halves W L2 traffic vs the 16-row version.
__global__ __launch_bounds__(256, 3)
void fused_kernel(const float* __restrict__ x,
                  const int* __restrict__ samples,
                  const unsigned short* __restrict__ Wp,
                  const float* __restrict__ b1,
                  const float* __restrict__ w2,
                  const float* __restrict__ b2,
                  float* __restrict__ out, int S)
{
    const int tid  = threadIdx.x;
    const int lane = tid & 63;
    const int wave = tid >> 6;
    const int cl   = lane & 15;
    const int hi   = lane >> 4;
    const int row0 = blockIdx.x * 128 + wave * 32;   // this wave's first output row

    const bf16x8* wgl = (const bf16x8*)Wp + lane;

    // ---- issue f=0 B-slab loads FIRST: their latency hides under the gather ----
    bf16x8 bc[8];
    #pragma unroll
    for (int kt = 0; kt < 8; ++kt) bc[kt] = wgl[kt * 64];

    // ---- sample indices for 32 rows: one coalesced load + 4 shfl broadcasts ----
    int imax = 2 * S - 1;
    int i0   = row0 * 2 + lane;
    int sidx = samples[i0 < imax ? i0 : imax];
    int ra0 = __shfl(sidx, 2 * cl,      64);
    int rb0 = __shfl(sidx, 2 * cl + 1,  64);
    int ra1 = __shfl(sidx, 2 * cl + 32, 64);
    int rb1 = __shfl(sidx, 2 * cl + 33, 64);
    const f32x4* xa0 = (const f32x4*)x + (size_t)ra0 * 64;
    const f32x4* xb0 = (const f32x4*)x + (size_t)rb0 * 64;
    const f32x4* xa1 = (const f32x4*)x + (size_t)ra1 * 64;
    const f32x4* xb1 = (const f32x4*)x + (size_t)rb1 * 64;

    // ---- direct per-lane A-fragment gather (verified in R5), two tiles ----
    // af{t}[kt][j] = bf16( x[ra{t}][kt*32+hi*8+j] * x[rb{t}][kt*32+hi*8+j] )
    bf16x8 af0[8], af1[8];
    #pragma unroll
    for (int g = 0; g < 4; ++g) {        // 2 kt per batch: 16 independent 16B loads
        f32x4 v[16];
        #pragma unroll
        for (int k = 0; k < 2; ++k) {
            int kt = g * 2 + k;
            int o  = kt * 8 + hi * 2;
            v[k * 8 + 0] = xa0[o];  v[k * 8 + 1] = xa0[o + 1];
            v[k * 8 + 2] = xb0[o];  v[k * 8 + 3] = xb0[o + 1];
            v[k * 8 + 4] = xa1[o];  v[k * 8 + 5] = xa1[o + 1];
            v[k * 8 + 6] = xb1[o];  v[k * 8 + 7] = xb1[o + 1];
        }
        #pragma unroll
        for (int k = 0; k < 2; ++k) {
            int kt = g * 2 + k;
            bf16x8 u0, u1;
            #pragma unroll
            for (int j = 0; j < 4; ++j) {
                u0[j]     = (short)f2bf(v[k*8+0][j] * v[k*8+2][j]);
                u0[4 + j] = (short)f2bf(v[k*8+1][j] * v[k*8+3][j]);
                u1[j]     = (short)f2bf(v[k*8+4][j] * v[k*8+6][j]);
                u1[4 + j] = (short)f2bf(v[k*8+5][j] * v[k*8+7][j]);
            }
            af0[kt] = u0;
            af1[kt] = u1;
        }
    }

    // ---- f-major W stream: two MFMA chains share each B-fragment ----
    float p00[4] = {0.f,0.f,0.f,0.f}, p10[4] = {0.f,0.f,0.f,0.f};
    float p01[4] = {0.f,0.f,0.f,0.f}, p11[4] = {0.f,0.f,0.f,0.f};

    #pragma unroll
    for (int f = 0; f < 16; ++f) {
        f32x4 a0 = (f32x4){0.f,0.f,0.f,0.f};
        f32x4 a1 = (f32x4){0.f,0.f,0.f,0.f};
        #pragma unroll
        for (int kt = 0; kt < 8; ++kt) {
            a0 = __builtin_amdgcn_mfma_f32_16x16x32_bf16(af0[kt], bc[kt], a0, 0, 0, 0);
            a1 = __builtin_amdgcn_mfma_f32_16x16x32_bf16(af1[kt], bc[kt], a1, 0, 0, 0);
        }
        // prefetch next slab while MFMAs drain
        if (f < 15) {
            #pragma unroll
            for (int kt = 0; kt < 8; ++kt) bc[kt] = wgl[(f + 1) * 512 + kt * 64];
        }
        float  b1v = b1[f * 16 + cl];
        float2 lw  = ((const float2*)w2)[f * 16 + cl];
        #pragma unroll
        for (int q = 0; q < 4; ++q) {
            float h0 = fmaxf(a0[q] + b1v, 0.f);
            float h1 = fmaxf(a1[q] + b1v, 0.f);
            p00[q] += h0 * lw.x;  p10[q] += h0 * lw.y;
            p01[q] += h1 * lw.x;  p11[q] += h1 * lw.y;
        }
    }

    // ---- 16-lane shuffle reduce + masked store, per tile ----
    #pragma unroll
    for (int m = 1; m < 16; m <<= 1) {
        #pragma unroll
        for (int q = 0; q < 4; ++q) {
            p00[q] += __shfl_xor(p00[q], m, 64);
            p10[q] += __shfl_xor(p10[q], m, 64);
            p01[q] += __shfl_xor(p01[q], m, 64);
            p11[q] += __shfl_xor(p11[q], m, 64);
        }
    }
    if (cl < 8) {
        int q = cl >> 1, j = cl & 1;
        int r0 = row0 + hi * 4 + q;
        if (r0 < S) out[r0 * 2 + j] = (j == 0 ? p00[q] : p10[q]) + b2[j];
        int r1 = row0 + 16 + hi * 4 + q;
        if (r1 < S) out[r1 * 2 + j] = (j == 0 ? p01[q] : p11[q]) + b2[j];
    }
}

extern "C" void kernel_launch(void* const* d_in, const int* in_sizes, int n_in,
                              void* d_out, int out_size, void* d_ws, size_t ws_size,
                              hipStream_t stream) {
    // setup_inputs order:
    // 0 x_feature, 1 edge_index(unused), 2 samples, 3 W1(u), 4 b1(u), 5 W2(u), 6 b2(u),
    // 7 lin1_W, 8 lin1_b, 9 lin2_W, 10 lin2_b
    const float* x       = (const float*)d_in[0];
    const int*   samples = (const int*)d_in[2];
    const float* lin1_W  = (const float*)d_in[7];
    const float* lin1_b  = (const float*)d_in[8];
    const float* lin2_W  = (const float*)d_in[9];
    const float* lin2_b  = (const float*)d_in[10];
    float* out = (float*)d_out;

    unsigned short* Wp = (unsigned short*)d_ws;   // 8192 * 16B = 128 KiB packed lin1_W
    const int S = in_sizes[2] / 2;                // 100000 sample pairs

    pack_w_kernel<<<32, 256, 0, stream>>>(lin1_W, Wp);

    const int nblk = (S + 127) / 128;             // 782 blocks, 128 rows each
    fused_kernel<<<nblk, 256, 0, stream>>>(x, samples, Wp, lin1_b, lin2_W, lin2_b, out, S);
}